// Round 1
// baseline (1685.782 us; speedup 1.0000x reference)
//
#include <hip/hip_runtime.h>
#include <cstddef>

// Problem constants (match reference: N=4096, D=2048, B=64)
#define NN 4096
#define DD 2048
#define BB 64
#define RPB 8                   // rows per block (persistent kernel)
#define NBLK (NN / RPB)         // 512 blocks = 2/CU on 256 CUs (co-resident)

constexpr float kAT     = 0.3f;
constexpr float kDSBETA = 1e-4f;
constexpr float kEB     = 0.5f;
constexpr float kEN     = 0.005f;   // 0.01 * E_B
constexpr float kEPS    = 0.01f;

__device__ __forceinline__ float wave_sum_f(float v) {
#pragma unroll
    for (int o = 32; o; o >>= 1) v += __shfl_xor(v, o, 64);
    return v;
}
__device__ __forceinline__ double wave_sum_d(double v) {
#pragma unroll
    for (int o = 32; o; o >>= 1) v += __shfl_xor(v, o, 64);
    return v;
}
__device__ __forceinline__ float wave_max_f(float v) {
#pragma unroll
    for (int o = 32; o; o >>= 1) v = fmaxf(v, __shfl_xor(v, o, 64));
    return v;
}
__device__ __forceinline__ float wave_min_f(float v) {
#pragma unroll
    for (int o = 32; o; o >>= 1) v = fminf(v, __shfl_xor(v, o, 64));
    return v;
}
__device__ __forceinline__ unsigned long long wave_max_u64(unsigned long long v) {
#pragma unroll
    for (int o = 32; o; o >>= 1) {
        const unsigned long long u = __shfl_xor(v, o, 64);
        v = (u > v) ? u : v;
    }
    return v;
}

// Decide whether `neighbors` arrived as byte-bools or int32.
__global__ void detect_nb(const unsigned char* __restrict__ nb, unsigned* __restrict__ flag) {
    unsigned v = 0;
    const int i0 = threadIdx.x * 256;
    for (int i = 0; i < 256; i++) {
        const int idx = i0 + i;
        if ((idx & 3) != 0) v |= nb[idx];
    }
    if (v != 0) atomicOr(flag, 1u);
}

// ---------------------------------------------------------------------------
// Persistent kernel, PLAIN launch (graph-capturable). All 64 steps in one
// dispatch. 512 blocks x 256 thr, 8 rows/block, W/R/M in registers (+AGPRs).
//
// Rendezvous protocol (v2 — centralized decode):
//   * Every block writes its per-step partial winner key into its OWN slot
//     pkey[t][bid] (write-once, RELAXED agent store). Keys are always nonzero
//     (act in (0,1)), so "slot != 0" doubles as the arrival flag — no counter
//     atomics at all.
//   * ONLY block 0 (wave 0) polls the 512 slots (8 relaxed loads/lane),
//     reduces the max, and publishes it to 8 replicated broadcast lines.
//   * All other blocks poll the single read-only broadcast word for their
//     bid&7 group (64 pollers/line, one writer — no line ping-pong).
//   The key is self-contained in one u64, and W/M/R never leave block-local
//   registers, so the whole protocol is correct with RELAXED ordering
//   (no acquire/release cache-maintenance on the poll path).
// ---------------------------------------------------------------------------
__global__ __launch_bounds__(256, 2) void som_persist(
    const float* __restrict__ x,            // B x D
    const float* __restrict__ W0,           // N x D initial
    const float* __restrict__ M0,           // N x D initial
    const float* __restrict__ R0,           // N x D initial
    const unsigned char* __restrict__ nbb,  // N x N (byte or int32 per *flag)
    const unsigned* __restrict__ flag,
    float* __restrict__ Wout,               // N x D final (d_out)
    unsigned long long* __restrict__ pkey,  // BB x NBLK write-once key slots
    unsigned long long* __restrict__ bcast) // BB x 8 replicated winner keys (stride 8 u64)
{
    const int tid  = threadIdx.x;
    const int wid  = tid >> 6;
    const int lane = tid & 63;
    const int bid  = (int)blockIdx.x;
    const int n0   = bid * RPB;
    const int col  = tid * 8;

    __shared__ double sdd[2][RPB][4];
    __shared__ float  sf[3][4];
    __shared__ unsigned long long skk[RPB];
    __shared__ unsigned long long sKey;

    const bool nb_byte = (*flag != 0);
    const int* nbi = (const int*)nbb;

    float w[RPB][8], r[RPB][8], m[RPB][8], xcur[8];

#pragma unroll
    for (int row = 0; row < RPB; ++row) {
        const size_t base = (size_t)(n0 + row) * DD + col;
        *(float4*)(&w[row][0]) = *(const float4*)(W0 + base);
        *(float4*)(&w[row][4]) = *(const float4*)(W0 + base + 4);
        *(float4*)(&r[row][0]) = *(const float4*)(R0 + base);
        *(float4*)(&r[row][4]) = *(const float4*)(R0 + base + 4);
        *(float4*)(&m[row][0]) = *(const float4*)(M0 + base);
        *(float4*)(&m[row][4]) = *(const float4*)(M0 + base + 4);
    }
    *(float4*)(xcur)     = *(const float4*)(x + col);
    *(float4*)(xcur + 4) = *(const float4*)(x + col + 4);

    // activation of this block's rows vs xcur -> post key into our own slot
    auto act_phase = [&](int slot) {
#pragma unroll
        for (int row = 0; row < RPB; ++row) {
            double pd = 0.0, ps = 0.0;
#pragma unroll
            for (int j = 0; j < 8; ++j) {
                const double d  = (double)xcur[j] - (double)w[row][j];
                const double rj = (double)r[row][j];
                pd += rj * d * d;
                ps += rj;
            }
            pd = wave_sum_d(pd); ps = wave_sum_d(ps);
            if (lane == 0) { sdd[0][row][wid] = pd; sdd[1][row][wid] = ps; }
        }
        __syncthreads();
        if (tid < RPB) {
            const int row = tid;
            const double td = sdd[0][row][0] + sdd[0][row][1] + sdd[0][row][2] + sdd[0][row][3];
            const double tr = sdd[1][row][0] + sdd[1][row][1] + sdd[1][row][2] + sdd[1][row][3];
            const double act = tr / (tr + td + 1e-7);
            const unsigned long long ab = (unsigned long long)__double_as_longlong(act);
            skk[row] = (ab & ~0xFFFULL) | (unsigned long long)(4095 - (n0 + row));
        }
        __syncthreads();
        if (tid == 0) {
            unsigned long long k = skk[0];
#pragma unroll
            for (int i = 1; i < RPB; ++i) k = (skk[i] > k) ? skk[i] : k;
            // write-once arrival+value in a single relaxed agent store
            __hip_atomic_store(&pkey[(size_t)slot * NBLK + bid], k,
                               __ATOMIC_RELAXED, __HIP_MEMORY_SCOPE_AGENT);
        }
        __syncthreads();
    };

    act_phase(0);

    for (int t = 0; t < BB; ++t) {
        // ---- rendezvous: master aggregates all 512 keys, others poll bcast ----
        if (wid == 0) {
            unsigned long long kmax = 0;
            if (bid == 0) {
                unsigned long long* pk = pkey + (size_t)t * NBLK;
                unsigned long long kk[8];
                int it = 0;
                while (true) {
                    bool miss = false;
#pragma unroll
                    for (int i = 0; i < 8; ++i) {
                        kk[i] = __hip_atomic_load(&pk[lane + 64 * i],
                                                  __ATOMIC_RELAXED, __HIP_MEMORY_SCOPE_AGENT);
                        miss |= (kk[i] == 0ull);
                    }
                    if (!__any(miss)) break;
                    if (++it > 2000000) break;          // safety valve: fail, don't hang
                    __builtin_amdgcn_s_sleep(1);
                }
#pragma unroll
                for (int i = 0; i < 8; ++i) kmax = (kk[i] > kmax) ? kk[i] : kmax;
                kmax = wave_max_u64(kmax);
                if (lane < 8)
                    __hip_atomic_store(&bcast[((size_t)t * 8 + lane) * 8], kmax,
                                       __ATOMIC_RELAXED, __HIP_MEMORY_SCOPE_AGENT);
            } else {
                const int rep = bid & 7;
                int it = 0;
                while ((kmax = __hip_atomic_load(&bcast[((size_t)t * 8 + rep) * 8],
                                                 __ATOMIC_RELAXED, __HIP_MEMORY_SCOPE_AGENT))
                       == 0ull) {
                    if (++it > 2000000) break;          // safety valve: fail, don't hang
                    __builtin_amdgcn_s_sleep(4);
                }
            }
            if (lane == 0) sKey = kmax;
        }
        __syncthreads();
        const unsigned long long k = sKey;
        __syncthreads();
        const double act_w = __longlong_as_double((long long)(k & ~0xFFFULL));
        const int winner   = 4095 - (int)(k & 0xFFFULL);

        if (act_w >= (double)kAT) {     // do_upd (grid-uniform)
#pragma unroll
            for (int row = 0; row < RPB; ++row) {
                const int n = n0 + row;
                float lr = 0.0f;
                if (n == winner) {
                    lr = kEB;
                } else {
                    const size_t off = (size_t)winner * NN + n;
                    const bool isnb = nb_byte ? (nbb[off] != 0) : (nbi[off] != 0);
                    if (isnb) lr = kEN;
                }
                if (lr != 0.0f) {       // block-uniform per row
                    const float c1 = lr * kDSBETA;
                    const float c2 = 1.0f - c1;
                    float psum = 0.0f, pmx = -INFINITY, pmn = INFINITY;
#pragma unroll
                    for (int j = 0; j < 8; ++j) {
                        const float d  = xcur[j] - w[row][j];
                        const float mv = c1 * fabsf(d) + c2 * m[row][j];
                        w[row][j] += lr * d;
                        m[row][j] = mv;
                        psum += mv;
                        pmx = fmaxf(pmx, mv);
                        pmn = fminf(pmn, mv);
                    }
                    psum = wave_sum_f(psum); pmx = wave_max_f(pmx); pmn = wave_min_f(pmn);
                    if (lane == 0) { sf[0][wid] = psum; sf[1][wid] = pmx; sf[2][wid] = pmn; }
                    __syncthreads();
                    const float ts  = sf[0][0] + sf[0][1] + sf[0][2] + sf[0][3];
                    const float tmx = fmaxf(fmaxf(sf[1][0], sf[1][1]), fmaxf(sf[1][2], sf[1][3]));
                    const float tmn = fminf(fminf(sf[2][0], sf[2][1]), fminf(sf[2][2], sf[2][3]));
                    __syncthreads();
                    const float av    = ts * (1.0f / (float)DD);
                    const float denom = kEPS * (tmx - tmn);
                    if (denom == 0.0f) {
#pragma unroll
                        for (int j = 0; j < 8; ++j) r[row][j] = 1.0f;
                    } else {
#pragma unroll
                        for (int j = 0; j < 8; ++j) {
                            float a = (m[row][j] - av) / denom;
                            a = fminf(fmaxf(a, -80.0f), 80.0f);
                            r[row][j] = 1.0f / (1.0f + expf(a));
                        }
                    }
                }
            }
        }

        if (t < BB - 1) {
            const size_t xb = (size_t)(t + 1) * DD + col;
            *(float4*)(xcur)     = *(const float4*)(x + xb);
            *(float4*)(xcur + 4) = *(const float4*)(x + xb + 4);
            act_phase(t + 1);
        }
    }

#pragma unroll
    for (int row = 0; row < RPB; ++row) {
        const size_t base = (size_t)(n0 + row) * DD + col;
        *(float4*)(Wout + base)     = *(float4*)(&w[row][0]);
        *(float4*)(Wout + base + 4) = *(float4*)(&w[row][4]);
    }
}

// ---------------------------------------------------------------------------
// Fallback: proven round-3 per-step kernel (65 dispatches, ~1.7 ms).
// ---------------------------------------------------------------------------
__global__ __launch_bounds__(256) void som_step(
    const float* __restrict__ x_upd, const float* __restrict__ x_act,
    float* __restrict__ W, float* __restrict__ M, float* __restrict__ R,
    const void* __restrict__ nb, const unsigned* __restrict__ flag,
    const unsigned long long* __restrict__ part_upd,
    unsigned long long* __restrict__ part_act)
{
    const int n   = blockIdx.x;
    const int tid = threadIdx.x;
    __shared__ float  sred[3][4];
    __shared__ double sredd[2][4];

    float lr = 0.0f;
    if (part_upd != nullptr) {
        unsigned long long k = part_upd[(size_t)(tid & 63) * 8];
        k = wave_max_u64(k);
        const double act_w = __longlong_as_double((long long)(k & ~0xFFFULL));
        const int winner   = 4095 - (int)(k & 0xFFFULL);
        if (act_w >= (double)kAT) {
            if (n == winner) lr = kEB;
            else {
                const size_t off = (size_t)winner * NN + n;
                const bool isnb = (*flag != 0)
                    ? (((const unsigned char*)nb)[off] != 0)
                    : (((const int*)nb)[off] != 0);
                if (isnb) lr = kEN;
            }
        }
    }
    const bool next = (x_act != nullptr);
    if (lr == 0.0f && !next) return;

    const size_t rowoff = (size_t)n * DD + (size_t)tid * 8;
    const size_t xoff   = (size_t)tid * 8;
    float w[8], r[8];
    *(float4*)(w)     = *(const float4*)(W + rowoff);
    *(float4*)(w + 4) = *(const float4*)(W + rowoff + 4);

    if (lr != 0.0f) {
        float m[8], xu[8], mnew[8];
        *(float4*)(m)      = *(const float4*)(M + rowoff);
        *(float4*)(m + 4)  = *(const float4*)(M + rowoff + 4);
        *(float4*)(xu)     = *(const float4*)(x_upd + xoff);
        *(float4*)(xu + 4) = *(const float4*)(x_upd + xoff + 4);
        const float c1 = lr * kDSBETA, c2 = 1.0f - c1;
        float psum = 0.0f, pmx = -INFINITY, pmn = INFINITY;
#pragma unroll
        for (int j = 0; j < 8; j++) {
            const float d = xu[j] - w[j];
            w[j] += lr * d;
            const float mv = c1 * fabsf(d) + c2 * m[j];
            mnew[j] = mv; psum += mv;
            pmx = fmaxf(pmx, mv); pmn = fminf(pmn, mv);
        }
        psum = wave_sum_f(psum); pmx = wave_max_f(pmx); pmn = wave_min_f(pmn);
        const int wid = tid >> 6, lane = tid & 63;
        if (lane == 0) { sred[0][wid] = psum; sred[1][wid] = pmx; sred[2][wid] = pmn; }
        __syncthreads();
        const float ts  = sred[0][0] + sred[0][1] + sred[0][2] + sred[0][3];
        const float tmx = fmaxf(fmaxf(sred[1][0], sred[1][1]), fmaxf(sred[1][2], sred[1][3]));
        const float tmn = fminf(fminf(sred[2][0], sred[2][1]), fminf(sred[2][2], sred[2][3]));
        __syncthreads();
        const float av = ts * (1.0f / (float)DD);
        const float denom = kEPS * (tmx - tmn);
        if (denom == 0.0f) {
#pragma unroll
            for (int j = 0; j < 8; j++) r[j] = 1.0f;
        } else {
#pragma unroll
            for (int j = 0; j < 8; j++) {
                float a = (mnew[j] - av) / denom;
                a = fminf(fmaxf(a, -80.0f), 80.0f);
                r[j] = 1.0f / (1.0f + expf(a));
            }
        }
        *(float4*)(W + rowoff)     = *(float4*)(w);
        *(float4*)(W + rowoff + 4) = *(float4*)(w + 4);
        *(float4*)(M + rowoff)     = *(float4*)(mnew);
        *(float4*)(M + rowoff + 4) = *(float4*)(mnew + 4);
        *(float4*)(R + rowoff)     = *(float4*)(r);
        *(float4*)(R + rowoff + 4) = *(float4*)(r + 4);
    } else {
        *(float4*)(r)     = *(const float4*)(R + rowoff);
        *(float4*)(r + 4) = *(const float4*)(R + rowoff + 4);
    }

    if (next) {
        float xn[8];
        *(float4*)(xn)     = *(const float4*)(x_act + xoff);
        *(float4*)(xn + 4) = *(const float4*)(x_act + xoff + 4);
        double pd = 0.0, ps = 0.0;
#pragma unroll
        for (int j = 0; j < 8; j++) {
            const double d  = (double)xn[j] - (double)w[j];
            const double rj = (double)r[j];
            pd += rj * d * d; ps += rj;
        }
        pd = wave_sum_d(pd); ps = wave_sum_d(ps);
        const int wid = tid >> 6, lane = tid & 63;
        if (lane == 0) { sredd[0][wid] = pd; sredd[1][wid] = ps; }
        __syncthreads();
        if (tid == 0) {
            const double td = sredd[0][0] + sredd[0][1] + sredd[0][2] + sredd[0][3];
            const double tr = sredd[1][0] + sredd[1][1] + sredd[1][2] + sredd[1][3];
            const double act = tr / (tr + td + 1e-7);
            const unsigned long long ab = (unsigned long long)__double_as_longlong(act);
            const unsigned long long kk = (ab & ~0xFFFULL) | (unsigned long long)(4095 - n);
            atomicMax(&part_act[(size_t)(n & 63) * 8], kk);
        }
    }
}

extern "C" void kernel_launch(void* const* d_in, const int* in_sizes, int n_in,
                              void* d_out, int out_size, void* d_ws, size_t ws_size,
                              hipStream_t stream) {
    const float*         x   = (const float*)d_in[0];
    const float*         W0  = (const float*)d_in[1];
    float*               M   = (float*)d_in[2];
    float*               R   = (float*)d_in[3];
    const unsigned char* nbb = (const unsigned char*)d_in[5];
    float*               W   = (float*)d_out;

    // ws layout (shared between paths, never used simultaneously):
    //   region A (270 KB): fallback `part` (66 slots x 64 x 8 u64)
    //                      OR persistent `pkey` (64 x 512 u64 = 256 KB)
    //   region B (32 KB):  persistent `bcast` (64 steps x 8 reps, stride 8 u64)
    //   region C: flag
    unsigned long long* part = (unsigned long long*)d_ws;
    const size_t part_bytes  = (size_t)66 * 64 * 8 * sizeof(unsigned long long); // 270 KB
    unsigned long long* bcast = (unsigned long long*)((char*)d_ws + part_bytes);
    const size_t cnt_bytes = (size_t)BB * 8 * 16 * sizeof(unsigned);             // 32 KB
    unsigned* flagp = (unsigned*)((char*)d_ws + part_bytes + cnt_bytes);

    hipMemsetAsync(d_ws, 0, part_bytes + cnt_bytes + 64, stream);
    detect_nb<<<1, 256, 0, stream>>>(nbb, flagp);

    // persistent path requires all 512 blocks co-resident (2 blocks/CU)
    int occ = 0;
    hipError_t qerr = hipOccupancyMaxActiveBlocksPerMultiprocessor(
        &occ, (const void*)som_persist, 256, 0);
    if (qerr == hipSuccess && occ >= 2) {
        som_persist<<<NBLK, 256, 0, stream>>>(x, W0, M, R, nbb, flagp, W, part, bcast);
        return;
    }

    // ---- fallback: proven 65-dispatch path ----
    hipMemcpyAsync(W, W0, sizeof(float) * (size_t)NN * DD, hipMemcpyDeviceToDevice, stream);
    som_step<<<NN, 256, 0, stream>>>(nullptr, x, W, M, R, nbb, flagp, nullptr, part);
    for (int t = 0; t < BB; t++) {
        const float* xu = x + (size_t)t * DD;
        const float* xa = (t < BB - 1) ? (x + (size_t)(t + 1) * DD) : nullptr;
        const unsigned long long* pu = part + (size_t)t * 64 * 8;
        unsigned long long*       pa = (t < BB - 1) ? (part + (size_t)(t + 1) * 64 * 8) : nullptr;
        som_step<<<NN, 256, 0, stream>>>(xu, xa, W, M, R, nbb, flagp, pu, pa);
    }
}

// Round 2
// 1673.825 us; speedup vs baseline: 1.0071x; 1.0071x over previous
//
#include <hip/hip_runtime.h>
#include <cstddef>

// Problem constants (match reference: N=4096, D=2048, B=64)
#define NN 4096
#define DD 2048
#define BB 64
#define RPB 8                   // rows per block (persistent kernel)
#define NBLK (NN / RPB)         // 512 blocks = 2/CU on 256 CUs (co-resident)

constexpr float kAT     = 0.3f;
constexpr float kDSBETA = 1e-4f;
constexpr float kEB     = 0.5f;
constexpr float kEN     = 0.005f;   // 0.01 * E_B
constexpr float kEPS    = 0.01f;

__device__ __forceinline__ float wave_sum_f(float v) {
#pragma unroll
    for (int o = 32; o; o >>= 1) v += __shfl_xor(v, o, 64);
    return v;
}
__device__ __forceinline__ double wave_sum_d(double v) {
#pragma unroll
    for (int o = 32; o; o >>= 1) v += __shfl_xor(v, o, 64);
    return v;
}
__device__ __forceinline__ float wave_max_f(float v) {
#pragma unroll
    for (int o = 32; o; o >>= 1) v = fmaxf(v, __shfl_xor(v, o, 64));
    return v;
}
__device__ __forceinline__ float wave_min_f(float v) {
#pragma unroll
    for (int o = 32; o; o >>= 1) v = fminf(v, __shfl_xor(v, o, 64));
    return v;
}
__device__ __forceinline__ unsigned long long wave_max_u64(unsigned long long v) {
#pragma unroll
    for (int o = 32; o; o >>= 1) {
        const unsigned long long u = __shfl_xor(v, o, 64);
        v = (u > v) ? u : v;
    }
    return v;
}

// Decide whether `neighbors` arrived as byte-bools or int32.
__global__ void detect_nb(const unsigned char* __restrict__ nb, unsigned* __restrict__ flag) {
    unsigned v = 0;
    const int i0 = threadIdx.x * 256;
    for (int i = 0; i < 256; i++) {
        const int idx = i0 + i;
        if ((idx & 3) != 0) v |= nb[idx];
    }
    if (v != 0) atomicOr(flag, 1u);
}

// ---------------------------------------------------------------------------
// Persistent kernel, PLAIN launch (graph-capturable). All 64 steps in one
// dispatch. 512 blocks x 256 thr, 8 rows/block, W/R/M in registers (+AGPRs).
//
// Rendezvous protocol (v3 — one-hop, RMW-free, fully decentralized):
//   * Every block writes its per-step partial winner key into its OWN slot
//     pkey[t][bid] (write-once, RELAXED agent store). Keys are always nonzero
//     (act in (0,1)), so "slot != 0" doubles as the arrival flag.
//   * EVERY block's wave 0 polls all 512 slots itself (8 coalesced relaxed
//     u64 loads per lane over a 4 KB read-only region) and reduces the max.
//     No aggregator, no broadcast stage, no counters, no atomic RMW —
//     exactly one producer-store -> consumer-load visibility hop per step.
//   The key is self-contained in one u64, and W/M/R never leave block-local
//   registers, so RELAXED ordering is sufficient end-to-end.
// ---------------------------------------------------------------------------
__global__ __launch_bounds__(256, 2) void som_persist(
    const float* __restrict__ x,            // B x D
    const float* __restrict__ W0,           // N x D initial
    const float* __restrict__ M0,           // N x D initial
    const float* __restrict__ R0,           // N x D initial
    const unsigned char* __restrict__ nbb,  // N x N (byte or int32 per *flag)
    const unsigned* __restrict__ flag,
    float* __restrict__ Wout,               // N x D final (d_out)
    unsigned long long* __restrict__ pkey)  // BB x NBLK write-once key slots
{
    const int tid  = threadIdx.x;
    const int wid  = tid >> 6;
    const int lane = tid & 63;
    const int bid  = (int)blockIdx.x;
    const int n0   = bid * RPB;
    const int col  = tid * 8;

    __shared__ double sdd[2][RPB][4];
    __shared__ float  sf[3][RPB][4];
    __shared__ unsigned long long skk[RPB];
    __shared__ unsigned long long sKey;

    const bool nb_byte = (*flag != 0);
    const int* nbi = (const int*)nbb;

    float w[RPB][8], r[RPB][8], m[RPB][8], xcur[8];

#pragma unroll
    for (int row = 0; row < RPB; ++row) {
        const size_t base = (size_t)(n0 + row) * DD + col;
        *(float4*)(&w[row][0]) = *(const float4*)(W0 + base);
        *(float4*)(&w[row][4]) = *(const float4*)(W0 + base + 4);
        *(float4*)(&r[row][0]) = *(const float4*)(R0 + base);
        *(float4*)(&r[row][4]) = *(const float4*)(R0 + base + 4);
        *(float4*)(&m[row][0]) = *(const float4*)(M0 + base);
        *(float4*)(&m[row][4]) = *(const float4*)(M0 + base + 4);
    }
    *(float4*)(xcur)     = *(const float4*)(x + col);
    *(float4*)(xcur + 4) = *(const float4*)(x + col + 4);

    // activation of this block's rows vs xcur -> post key into our own slot.
    // NOTE: no trailing barrier — the rendezvous __syncthreads at the top of
    // the step loop provides the ordering (tid 0 must arrive there, so its
    // pkey store and skk read have completed before any wave proceeds).
    auto act_phase = [&](int slot) {
#pragma unroll
        for (int row = 0; row < RPB; ++row) {
            double pd = 0.0, ps = 0.0;
#pragma unroll
            for (int j = 0; j < 8; ++j) {
                const double d  = (double)xcur[j] - (double)w[row][j];
                const double rj = (double)r[row][j];
                pd += rj * d * d;
                ps += rj;
            }
            pd = wave_sum_d(pd); ps = wave_sum_d(ps);
            if (lane == 0) { sdd[0][row][wid] = pd; sdd[1][row][wid] = ps; }
        }
        __syncthreads();
        if (tid < RPB) {
            const int row = tid;
            const double td = sdd[0][row][0] + sdd[0][row][1] + sdd[0][row][2] + sdd[0][row][3];
            const double tr = sdd[1][row][0] + sdd[1][row][1] + sdd[1][row][2] + sdd[1][row][3];
            const double act = tr / (tr + td + 1e-7);
            const unsigned long long ab = (unsigned long long)__double_as_longlong(act);
            skk[row] = (ab & ~0xFFFULL) | (unsigned long long)(4095 - (n0 + row));
        }
        __syncthreads();
        if (tid == 0) {
            unsigned long long k = skk[0];
#pragma unroll
            for (int i = 1; i < RPB; ++i) k = (skk[i] > k) ? skk[i] : k;
            // write-once arrival+value in a single relaxed agent store
            __hip_atomic_store(&pkey[(size_t)slot * NBLK + bid], k,
                               __ATOMIC_RELAXED, __HIP_MEMORY_SCOPE_AGENT);
        }
    };

    act_phase(0);

    float xn[8];
    for (int t = 0; t < BB; ++t) {
        const bool has_next = (t < BB - 1);
        // issue next-sample loads BEFORE the wait: HBM latency hides under poll
        if (has_next) {
            const size_t xb = (size_t)(t + 1) * DD + col;
            *(float4*)(xn)     = *(const float4*)(x + xb);
            *(float4*)(xn + 4) = *(const float4*)(x + xb + 4);
        }

        // ---- rendezvous: every block polls all 512 write-once slots ----
        if (wid == 0) {
            unsigned long long* pk = pkey + (size_t)t * NBLK;
            unsigned long long kk[8];
            int it = 0;
            while (true) {
                bool miss = false;
#pragma unroll
                for (int i = 0; i < 8; ++i) {
                    kk[i] = __hip_atomic_load(&pk[lane + 64 * i],
                                              __ATOMIC_RELAXED, __HIP_MEMORY_SCOPE_AGENT);
                    miss |= (kk[i] == 0ull);
                }
                if (!__any(miss)) break;
                if (++it > 2000000) break;              // safety valve: fail, don't hang
                __builtin_amdgcn_s_sleep(1);
            }
            unsigned long long kmax = 0;
#pragma unroll
            for (int i = 0; i < 8; ++i) kmax = (kk[i] > kmax) ? kk[i] : kmax;
            kmax = wave_max_u64(kmax);
            if (lane == 0) sKey = kmax;
        }
        __syncthreads();
        const unsigned long long k = sKey;
        // no second barrier needed: the next write to sKey happens only after
        // the next rendezvous barrier, which every wave must reach first.
        const double act_w = __longlong_as_double((long long)(k & ~0xFFFULL));
        const int winner   = 4095 - (int)(k & 0xFFFULL);

        if (act_w >= (double)kAT) {     // do_upd (grid-uniform)
            // vectorized nb-row read: this block's 8 entries are contiguous
            int nbr[RPB];
            {
                const size_t off = (size_t)winner * NN + n0;
                if (nb_byte) {
                    const unsigned long long nb8 = *(const unsigned long long*)(nbb + off);
#pragma unroll
                    for (int i = 0; i < RPB; ++i)
                        nbr[i] = (int)((nb8 >> (8 * i)) & 0xFFull);
                } else {
                    const int4 a = *(const int4*)(nbi + off);
                    const int4 b = *(const int4*)(nbi + off + 4);
                    nbr[0] = a.x; nbr[1] = a.y; nbr[2] = a.z; nbr[3] = a.w;
                    nbr[4] = b.x; nbr[5] = b.y; nbr[6] = b.z; nbr[7] = b.w;
                }
            }
            float lrs[RPB];
            bool any = false;
            // pass 1: elementwise W/M updates + per-row partial reductions
#pragma unroll
            for (int row = 0; row < RPB; ++row) {
                const int n = n0 + row;
                float lr = 0.0f;
                if (n == winner)      lr = kEB;
                else if (nbr[row])    lr = kEN;
                lrs[row] = lr;
                if (lr != 0.0f) {       // block-uniform per row
                    any = true;
                    const float c1 = lr * kDSBETA;
                    const float c2 = 1.0f - c1;
                    float psum = 0.0f, pmx = -INFINITY, pmn = INFINITY;
#pragma unroll
                    for (int j = 0; j < 8; ++j) {
                        const float d  = xcur[j] - w[row][j];
                        const float mv = c1 * fabsf(d) + c2 * m[row][j];
                        w[row][j] += lr * d;
                        m[row][j] = mv;
                        psum += mv;
                        pmx = fmaxf(pmx, mv);
                        pmn = fminf(pmn, mv);
                    }
                    psum = wave_sum_f(psum); pmx = wave_max_f(pmx); pmn = wave_min_f(pmn);
                    if (lane == 0) { sf[0][row][wid] = psum; sf[1][row][wid] = pmx; sf[2][row][wid] = pmn; }
                }
            }
            if (any) {                  // block-uniform
                __syncthreads();
                // pass 2: per-row totals (LDS broadcast reads) + R update
#pragma unroll
                for (int row = 0; row < RPB; ++row) {
                    if (lrs[row] != 0.0f) {
                        const float ts  = sf[0][row][0] + sf[0][row][1] + sf[0][row][2] + sf[0][row][3];
                        const float tmx = fmaxf(fmaxf(sf[1][row][0], sf[1][row][1]),
                                                fmaxf(sf[1][row][2], sf[1][row][3]));
                        const float tmn = fminf(fminf(sf[2][row][0], sf[2][row][1]),
                                                fminf(sf[2][row][2], sf[2][row][3]));
                        const float av    = ts * (1.0f / (float)DD);
                        const float denom = kEPS * (tmx - tmn);
                        if (denom == 0.0f) {
#pragma unroll
                            for (int j = 0; j < 8; ++j) r[row][j] = 1.0f;
                        } else {
#pragma unroll
                            for (int j = 0; j < 8; ++j) {
                                float a = (m[row][j] - av) / denom;
                                a = fminf(fmaxf(a, -80.0f), 80.0f);
                                r[row][j] = 1.0f / (1.0f + expf(a));
                            }
                        }
                    }
                }
            }
        }

        if (has_next) {
#pragma unroll
            for (int j = 0; j < 8; ++j) xcur[j] = xn[j];
            act_phase(t + 1);
        }
    }

#pragma unroll
    for (int row = 0; row < RPB; ++row) {
        const size_t base = (size_t)(n0 + row) * DD + col;
        *(float4*)(Wout + base)     = *(float4*)(&w[row][0]);
        *(float4*)(Wout + base + 4) = *(float4*)(&w[row][4]);
    }
}

// ---------------------------------------------------------------------------
// Fallback: proven round-3 per-step kernel (65 dispatches, ~1.7 ms).
// ---------------------------------------------------------------------------
__global__ __launch_bounds__(256) void som_step(
    const float* __restrict__ x_upd, const float* __restrict__ x_act,
    float* __restrict__ W, float* __restrict__ M, float* __restrict__ R,
    const void* __restrict__ nb, const unsigned* __restrict__ flag,
    const unsigned long long* __restrict__ part_upd,
    unsigned long long* __restrict__ part_act)
{
    const int n   = blockIdx.x;
    const int tid = threadIdx.x;
    __shared__ float  sred[3][4];
    __shared__ double sredd[2][4];

    float lr = 0.0f;
    if (part_upd != nullptr) {
        unsigned long long k = part_upd[(size_t)(tid & 63) * 8];
        k = wave_max_u64(k);
        const double act_w = __longlong_as_double((long long)(k & ~0xFFFULL));
        const int winner   = 4095 - (int)(k & 0xFFFULL);
        if (act_w >= (double)kAT) {
            if (n == winner) lr = kEB;
            else {
                const size_t off = (size_t)winner * NN + n;
                const bool isnb = (*flag != 0)
                    ? (((const unsigned char*)nb)[off] != 0)
                    : (((const int*)nb)[off] != 0);
                if (isnb) lr = kEN;
            }
        }
    }
    const bool next = (x_act != nullptr);
    if (lr == 0.0f && !next) return;

    const size_t rowoff = (size_t)n * DD + (size_t)tid * 8;
    const size_t xoff   = (size_t)tid * 8;
    float w[8], r[8];
    *(float4*)(w)     = *(const float4*)(W + rowoff);
    *(float4*)(w + 4) = *(const float4*)(W + rowoff + 4);

    if (lr != 0.0f) {
        float m[8], xu[8], mnew[8];
        *(float4*)(m)      = *(const float4*)(M + rowoff);
        *(float4*)(m + 4)  = *(const float4*)(M + rowoff + 4);
        *(float4*)(xu)     = *(const float4*)(x_upd + xoff);
        *(float4*)(xu + 4) = *(const float4*)(x_upd + xoff + 4);
        const float c1 = lr * kDSBETA, c2 = 1.0f - c1;
        float psum = 0.0f, pmx = -INFINITY, pmn = INFINITY;
#pragma unroll
        for (int j = 0; j < 8; j++) {
            const float d = xu[j] - w[j];
            w[j] += lr * d;
            const float mv = c1 * fabsf(d) + c2 * m[j];
            mnew[j] = mv; psum += mv;
            pmx = fmaxf(pmx, mv); pmn = fminf(pmn, mv);
        }
        psum = wave_sum_f(psum); pmx = wave_max_f(pmx); pmn = wave_min_f(pmn);
        const int wid = tid >> 6, lane = tid & 63;
        if (lane == 0) { sred[0][wid] = psum; sred[1][wid] = pmx; sred[2][wid] = pmn; }
        __syncthreads();
        const float ts  = sred[0][0] + sred[0][1] + sred[0][2] + sred[0][3];
        const float tmx = fmaxf(fmaxf(sred[1][0], sred[1][1]), fmaxf(sred[1][2], sred[1][3]));
        const float tmn = fminf(fminf(sred[2][0], sred[2][1]), fminf(sred[2][2], sred[2][3]));
        __syncthreads();
        const float av = ts * (1.0f / (float)DD);
        const float denom = kEPS * (tmx - tmn);
        if (denom == 0.0f) {
#pragma unroll
            for (int j = 0; j < 8; j++) r[j] = 1.0f;
        } else {
#pragma unroll
            for (int j = 0; j < 8; j++) {
                float a = (mnew[j] - av) / denom;
                a = fminf(fmaxf(a, -80.0f), 80.0f);
                r[j] = 1.0f / (1.0f + expf(a));
            }
        }
        *(float4*)(W + rowoff)     = *(float4*)(w);
        *(float4*)(W + rowoff + 4) = *(float4*)(w + 4);
        *(float4*)(M + rowoff)     = *(float4*)(mnew);
        *(float4*)(M + rowoff + 4) = *(float4*)(mnew + 4);
        *(float4*)(R + rowoff)     = *(float4*)(r);
        *(float4*)(R + rowoff + 4) = *(float4*)(r + 4);
    } else {
        *(float4*)(r)     = *(const float4*)(R + rowoff);
        *(float4*)(r + 4) = *(const float4*)(R + rowoff + 4);
    }

    if (next) {
        float xn[8];
        *(float4*)(xn)     = *(const float4*)(x_act + xoff);
        *(float4*)(xn + 4) = *(const float4*)(x_act + xoff + 4);
        double pd = 0.0, ps = 0.0;
#pragma unroll
        for (int j = 0; j < 8; j++) {
            const double d  = (double)xn[j] - (double)w[j];
            const double rj = (double)r[j];
            pd += rj * d * d; ps += rj;
        }
        pd = wave_sum_d(pd); ps = wave_sum_d(ps);
        const int wid = tid >> 6, lane = tid & 63;
        if (lane == 0) { sredd[0][wid] = pd; sredd[1][wid] = ps; }
        __syncthreads();
        if (tid == 0) {
            const double td = sredd[0][0] + sredd[0][1] + sredd[0][2] + sredd[0][3];
            const double tr = sredd[1][0] + sredd[1][1] + sredd[1][2] + sredd[1][3];
            const double act = tr / (tr + td + 1e-7);
            const unsigned long long ab = (unsigned long long)__double_as_longlong(act);
            const unsigned long long kk = (ab & ~0xFFFULL) | (unsigned long long)(4095 - n);
            atomicMax(&part_act[(size_t)(n & 63) * 8], kk);
        }
    }
}

extern "C" void kernel_launch(void* const* d_in, const int* in_sizes, int n_in,
                              void* d_out, int out_size, void* d_ws, size_t ws_size,
                              hipStream_t stream) {
    const float*         x   = (const float*)d_in[0];
    const float*         W0  = (const float*)d_in[1];
    float*               M   = (float*)d_in[2];
    float*               R   = (float*)d_in[3];
    const unsigned char* nbb = (const unsigned char*)d_in[5];
    float*               W   = (float*)d_out;

    // ws layout (shared between paths, never used simultaneously):
    //   region A (270 KB): fallback `part` (66 slots x 64 x 8 u64)
    //                      OR persistent `pkey` (64 x 512 u64 = 256 KB)
    //   region B (32 KB):  reserved
    //   region C: flag
    unsigned long long* part = (unsigned long long*)d_ws;
    const size_t part_bytes  = (size_t)66 * 64 * 8 * sizeof(unsigned long long); // 270 KB
    const size_t cnt_bytes = (size_t)BB * 8 * 16 * sizeof(unsigned);             // 32 KB
    unsigned* flagp = (unsigned*)((char*)d_ws + part_bytes + cnt_bytes);

    hipMemsetAsync(d_ws, 0, part_bytes + cnt_bytes + 64, stream);
    detect_nb<<<1, 256, 0, stream>>>(nbb, flagp);

    // persistent path requires all 512 blocks co-resident (2 blocks/CU)
    int occ = 0;
    hipError_t qerr = hipOccupancyMaxActiveBlocksPerMultiprocessor(
        &occ, (const void*)som_persist, 256, 0);
    if (qerr == hipSuccess && occ >= 2) {
        som_persist<<<NBLK, 256, 0, stream>>>(x, W0, M, R, nbb, flagp, W, part);
        return;
    }

    // ---- fallback: proven 65-dispatch path ----
    hipMemcpyAsync(W, W0, sizeof(float) * (size_t)NN * DD, hipMemcpyDeviceToDevice, stream);
    som_step<<<NN, 256, 0, stream>>>(nullptr, x, W, M, R, nbb, flagp, nullptr, part);
    for (int t = 0; t < BB; t++) {
        const float* xu = x + (size_t)t * DD;
        const float* xa = (t < BB - 1) ? (x + (size_t)(t + 1) * DD) : nullptr;
        const unsigned long long* pu = part + (size_t)t * 64 * 8;
        unsigned long long*       pa = (t < BB - 1) ? (part + (size_t)(t + 1) * 64 * 8) : nullptr;
        som_step<<<NN, 256, 0, stream>>>(xu, xa, W, M, R, nbb, flagp, pu, pa);
    }
}